// Round 9
// baseline (105.522 us; speedup 1.0000x reference)
//
#include <hip/hip_runtime.h>

// Legendre projection: out[n, dim*128 + deg] = P_deg(2*x[n,dim] - 1)
// 1,048,576 (n,dim) segments x 128 fp32 = 512 MiB output. Write-bound.
// History: R4 scatter-drain 20 waves/CU = 102.2 us; R8 contiguous-drain
// 1 wave/SIMD = 104.4 us (latency-crippled by the serial recurrence chain);
// R6 32 waves/CU = 115; plain stores +3% (R7).
// R9: contiguous drain + 2 waves/SIMD. 128-thr blocks; both waves run the
// same 64-segment recurrence (chain is latency-long but issue-cheap);
// wave 0 writes degree-words 0-15, wave 1 words 16-31. One barrier, then
// both waves drain 32 KB fully contiguously (16 nt instrs x 1 KB).
// LDS 33.8 KB -> 4 blocks/CU = 8 waves/CU, phases staggered across blocks.

#define DEG1 128

typedef float f32x4 __attribute__((ext_vector_type(4)));

__global__ __launch_bounds__(128) void LegendreProjection_48644799594943_kernel(
    const float* __restrict__ x, float* __restrict__ out) {
    // 64 segments x 33 f32x4 rows (32 data + 1 pad) = 33792 B.
    // Padded rows keep write (row-walk) and read (column-within-seg) at the
    // conflict-free b128 floor.
    __shared__ f32x4 lds[64 * 33];

    const int tid  = threadIdx.x;        // 0..127
    const int wv   = tid >> 6;           // wave 0 or 1
    const int lane = tid & 63;           // lane owns segment `lane`
    const int seg0 = blockIdx.x * 64;    // block's 64 segments

    const float xs = 2.0f * x[seg0 + lane] - 1.0f;

    // --- compute: both waves run the full recurrence for their segment;
    //     wave 0 stages degree-words 0-15, wave 1 words 16-31 ---
    float pm = 1.0f;  // P_{deg-1}
    float pc = xs;    // P_deg
#pragma unroll
    for (int w = 0; w < 32; ++w) {
        f32x4 q;
#pragma unroll
        for (int j = 0; j < 4; ++j) {
            const int deg = w * 4 + j;
            float val;
            if (deg == 0) {
                val = 1.0f;
            } else if (deg == 1) {
                val = xs;
            } else {
                // P_{n+1} = ((2n+1) x P_n - n P_{n-1}) / (n+1), n = deg-1
                const float nf = (float)(deg - 1);
                val = ((2.0f * nf + 1.0f) * xs * pc - nf * pm) * (1.0f / (nf + 1.0f));
                pm = pc;
                pc = val;
            }
            q[j] = val;
        }
        if ((w >> 4) == wv) {            // wave-uniform write guard
            lds[lane * 33 + w] = q;
        }
    }

    __syncthreads();

    // --- drain: 16 nt-store instrs x 128 threads, jointly walking the
    //     block's 32 KB output linearly; each wave-instr = 1 KB contiguous ---
    f32x4* outv = reinterpret_cast<f32x4*>(out) + (size_t)seg0 * (DEG1 / 4);
#pragma unroll
    for (int k = 0; k < 16; ++k) {
        const int f = k * 128 + tid;     // f32x4 index within the 2048-word tile
        const int s = f >> 5;            // local segment (32 words each)
        const int w = f & 31;            // word within segment
        const f32x4 d = lds[s * 33 + w];
        __builtin_nontemporal_store(d, &outv[f]);
    }
}

extern "C" void kernel_launch(void* const* d_in, const int* in_sizes, int n_in,
                              void* d_out, int out_size, void* d_ws, size_t ws_size,
                              hipStream_t stream) {
    const float* x = (const float*)d_in[0];
    float* out = (float*)d_out;
    const int total = in_sizes[0];   // 1,048,576 segments
    const int grid = total / 64;     // 64 segments per 2-wave block
    LegendreProjection_48644799594943_kernel<<<grid, 128, 0, stream>>>(x, out);
}

// Round 10
// 102.951 us; speedup vs baseline: 1.0250x; 1.0250x over previous
//
#include <hip/hip_runtime.h>

// Legendre projection: out[n, dim*128 + deg] = P_deg(2*x[n,dim] - 1)
// 1,048,576 (n,dim) segments x 128 fp32 = 512 MiB output. Write-bound.
// Plateau map: R4 scatter/20w = 102.2 us; R8 contig/4w = 104.4; R9
// contig/8w = 105.5; R6 32w/redundant = 115; plain stores +3%.
// Store pattern, wave depth, nt — all exonerated. R10 attacks dispatch
// churn: 1024 persistent-ish blocks (4/CU), each runs the proven R4
// wave-pipeline over 4 consecutive tiles (512 KB contiguous output per
// block), x prefetched for all tiles, no barriers — store issue never
// pauses from first chunk to last.

#define DEG1 128

typedef float f32x4 __attribute__((ext_vector_type(4)));

__global__ __launch_bounds__(256) void LegendreProjection_48644799594943_kernel(
    const float* __restrict__ x, float* __restrict__ out) {
    // [wave][seg][slot], slot = vec ^ (seg&7). 4 * 64 * 8 * 16B = 32 KB.
    __shared__ f32x4 lds[4][64][8];

    const int tid  = threadIdx.x;
    const int wave = tid >> 6;
    const int lane = tid & 63;
    // Block owns 4 tiles x 256 segments = 1024 consecutive segments.
    const int blk0 = blockIdx.x * 1024;

    // Prefetch x for all 4 tiles (static indices).
    float xsa[4];
#pragma unroll
    for (int t = 0; t < 4; ++t) {
        xsa[t] = 2.0f * x[blk0 + t * 256 + wave * 64 + lane] - 1.0f;
    }

    f32x4 (*my)[8] = lds[wave];
    f32x4* outv = reinterpret_cast<f32x4*>(out);

#pragma unroll
    for (int t = 0; t < 4; ++t) {
        const int seg0 = blk0 + t * 256 + wave * 64;  // this wave's 64 segments
        const float xs = xsa[t];

        float pm = 1.0f;  // P_{deg-1}
        float pc = xs;    // P_deg

#pragma unroll
        for (int c = 0; c < 4; ++c) {
            // --- compute 32 degrees, write swizzled to LDS ---
#pragma unroll
            for (int v = 0; v < 8; ++v) {
                f32x4 q;
#pragma unroll
                for (int j = 0; j < 4; ++j) {
                    const int deg = c * 32 + v * 4 + j;
                    float val;
                    if (deg == 0) {
                        val = 1.0f;
                    } else if (deg == 1) {
                        val = xs;
                    } else {
                        // P_{n+1} = ((2n+1) x P_n - n P_{n-1}) / (n+1), n = deg-1
                        const float nf = (float)(deg - 1);
                        val = ((2.0f * nf + 1.0f) * xs * pc - nf * pm) * (1.0f / (nf + 1.0f));
                        pm = pc;
                        pc = val;
                    }
                    q[j] = val;
                }
                my[lane][v ^ (lane & 7)] = q;  // aligned 8-lane runs -> 8 bank groups
            }

            // --- transposed drain: 8 nt instrs, each = 8 aligned full 128B lines ---
#pragma unroll
            for (int k = 0; k < 8; ++k) {
                const int s = k * 8 + (lane >> 3);  // local segment
                const int v = lane & 7;             // float4 index within chunk
                const f32x4 q = my[s][v ^ (s & 7)];
                __builtin_nontemporal_store(
                    q, &outv[(size_t)(seg0 + s) * (DEG1 / 4) + c * 8 + v]);
            }
        }
    }
}

extern "C" void kernel_launch(void* const* d_in, const int* in_sizes, int n_in,
                              void* d_out, int out_size, void* d_ws, size_t ws_size,
                              hipStream_t stream) {
    const float* x = (const float*)d_in[0];
    float* out = (float*)d_out;
    const int total = in_sizes[0];   // 1,048,576 segments
    const int grid = total / 1024;   // 1024 segments per block (4 tiles x 256)
    LegendreProjection_48644799594943_kernel<<<grid, 256, 0, stream>>>(x, out);
}

// Round 11
// 101.367 us; speedup vs baseline: 1.0410x; 1.0156x over previous
//
#include <hip/hip_runtime.h>

// Legendre projection: out[n, dim*128 + deg] = P_deg(2*x[n,dim] - 1)
// 1,048,576 (n,dim) segments x 128 fp32 = 512 MiB output. Write-bound.
// Plateau 102-105 us (~5.3 TB/s) across: scatter/contig drain, 4-32
// waves/CU, nt/plain, persistent grid. Memset ref: 6.7 TB/s.
// R11: RFO/write-granule test. All prior fast variants wrote 128 B
// contiguous per lane-run; if the effective write-allocate granule is
// 256 B, each run fetches the missing half (~25% read amplification ->
// exactly the plateau). Here: chunk = 64 degrees (256 B/seg staged,
// 16 KB/wave, no barriers), drain instrs use 16-lane runs = 256 B
// contiguous (4 segs/instr). Only {run length, chunk size, occupancy}
// change vs R4.

#define DEG1 128

typedef float f32x4 __attribute__((ext_vector_type(4)));

__global__ __launch_bounds__(256) void LegendreProjection_48644799594943_kernel(
    const float* __restrict__ x, float* __restrict__ out) {
    // Per wave: 64 segs x 16 f32x4 (one 64-degree chunk) = 16 KB.
    // Flat idx = seg*16 + (w ^ (seg&15)).
    // Write (lane=seg, fixed w): dword-bank 4*(w^(lane&15))%32 — each
    // 8-lane group covers all 32 banks -> b128 conflict-free floor.
    // Read (instr k): 16-lane groups span w'=0..15 -> all banks covered.
    __shared__ f32x4 lds[4][1024];

    const int tid  = threadIdx.x;
    const int wave = tid >> 6;
    const int lane = tid & 63;
    const int seg0 = (blockIdx.x * 4 + wave) * 64;  // this wave's 64 segments

    const float xs = 2.0f * x[seg0 + lane] - 1.0f;

    f32x4* my = lds[wave];
    f32x4* outv = reinterpret_cast<f32x4*>(out);

    float pm = 1.0f;  // P_{deg-1}
    float pc = xs;    // P_deg

#pragma unroll
    for (int c = 0; c < 2; ++c) {
        // --- compute 64 degrees for my segment, write swizzled to LDS ---
#pragma unroll
        for (int w = 0; w < 16; ++w) {
            f32x4 q;
#pragma unroll
            for (int j = 0; j < 4; ++j) {
                const int deg = c * 64 + w * 4 + j;
                float val;
                if (deg == 0) {
                    val = 1.0f;
                } else if (deg == 1) {
                    val = xs;
                } else {
                    // P_{n+1} = ((2n+1) x P_n - n P_{n-1}) / (n+1), n = deg-1
                    const float nf = (float)(deg - 1);
                    val = ((2.0f * nf + 1.0f) * xs * pc - nf * pm) * (1.0f / (nf + 1.0f));
                    pm = pc;
                    pc = val;
                }
                q[j] = val;
            }
            my[lane * 16 + (w ^ (lane & 15))] = q;
        }

        // --- drain: 16 nt instrs, each = 4 runs of 256 B contiguous ---
#pragma unroll
        for (int k = 0; k < 16; ++k) {
            const int s  = k * 4 + (lane >> 4);  // local segment
            const int wd = lane & 15;            // f32x4 word within chunk
            const f32x4 d = my[s * 16 + (wd ^ (s & 15))];
            // out word: seg*32 + c*16 + wd ; 16 lanes -> 256 B contiguous
            __builtin_nontemporal_store(
                d, &outv[(size_t)(seg0 + s) * (DEG1 / 4) + c * 16 + wd]);
        }
    }
}

extern "C" void kernel_launch(void* const* d_in, const int* in_sizes, int n_in,
                              void* d_out, int out_size, void* d_ws, size_t ws_size,
                              hipStream_t stream) {
    const float* x = (const float*)d_in[0];
    float* out = (float*)d_out;
    const int total = in_sizes[0];   // 1,048,576 segments
    const int grid = total / 256;    // 256 segments per block (4 waves x 64)
    LegendreProjection_48644799594943_kernel<<<grid, 256, 0, stream>>>(x, out);
}